// Round 4
// baseline (5152.776 us; speedup 1.0000x reference)
//
#include <hip/hip_runtime.h>
#include <hip/hip_fp16.h>

typedef _Float16 f16;
typedef _Float16 f16x8 __attribute__((ext_vector_type(8)));
typedef float f32x16 __attribute__((ext_vector_type(16)));

#define T_N 512
#define DSTEPS 48
#define TOTSTEPS 560
#define NWG 128

// ---- ws layout (bytes) ----
#define OFF_WHHE 0ull
#define SZ_WHH   (4096ull*1024*2)          // 8 MB
#define OFF_WHHD (OFF_WHHE + SZ_WHH)
#define OFF_WIHE (OFF_WHHD + SZ_WHH)
#define SZ_WIH   (4096ull*64*2)            // 512 KB
#define OFF_WIHD (OFF_WIHE + SZ_WIH)
#define OFF_WFC  (OFF_WIHD + SZ_WIH)
#define SZ_WFC   (64ull*1024*2)            // 128 KB
#define OFF_XP   (OFF_WFC + SZ_WFC)
#define SZ_XP    (512ull*4096*2)           // 4 MB
#define OFF_Y0   (OFF_XP + SZ_XP)
#define SZ_Y0    (4096ull*2)
#define OFF_BE   (OFF_Y0 + SZ_Y0)
#define OFF_BD   (OFF_BE + 4096ull*4)
#define OFF_CNT  (OFF_BD + 4096ull*4)
#define SZ_CNT   (561ull*2*4)              // step-release counters [t][g]
#define OFF_H    ((OFF_CNT + SZ_CNT + 255ull) & ~255ull)
// h of step t: 65536 f16 at OFF_H + t*131072; group g at +g*32768 f16,
// group layout [w_src(64)][b(32)][u(16)]

// ============================ prologue ============================
__global__ void prologue(const float* __restrict__ x, const float* __restrict__ y0,
    const float* __restrict__ wihE, const float* __restrict__ whhE,
    const float* __restrict__ bihE, const float* __restrict__ bhhE,
    const float* __restrict__ wihD, const float* __restrict__ whhD,
    const float* __restrict__ bihD, const float* __restrict__ bhhD,
    const float* __restrict__ wfc, char* __restrict__ ws)
{
  const long long gid = (long long)blockIdx.x * 256 + threadIdx.x;
  const long long gsz = (long long)gridDim.x * 256;
  f16* whhEp = (f16*)(ws + OFF_WHHE);
  f16* whhDp = (f16*)(ws + OFF_WHHD);
  f16* wihEp = (f16*)(ws + OFF_WIHE);
  f16* wihDp = (f16*)(ws + OFF_WIHD);
  f16* wfcp  = (f16*)(ws + OFF_WFC);
  f16* xp    = (f16*)(ws + OFF_XP);
  f16* y0p   = (f16*)(ws + OFF_Y0);
  float* be  = (float*)(ws + OFF_BE);
  float* bd  = (float*)(ws + OFF_BD);
  unsigned* cnt = (unsigned*)(ws + OFF_CNT);

  // Whh packs: idx = w*65536 + ks*32768 + i*16384 + kk*512 + lane*8 + j
  for (long long idx = gid; idx < 4194304ll; idx += gsz) {
    int j = (int)idx & 7, l = (int)(idx >> 3) & 63, kk = (int)(idx >> 9) & 31;
    int i = (int)(idx >> 14) & 1, ks = (int)(idx >> 15) & 1, w = (int)(idx >> 16);
    int nl = i * 32 + (l & 31);
    int grow = (nl >> 4) * 1024 + w * 16 + (nl & 15);
    int k = ks * 512 + kk * 16 + ((l >> 5) << 3) + j;
    whhEp[idx] = (f16)whhE[(long long)grow * 1024 + k];
    whhDp[idx] = (f16)whhD[(long long)grow * 1024 + k];
  }
  // Wih packs
  for (long long idx = gid; idx < 262144ll; idx += gsz) {
    int j = (int)idx & 7, l = (int)(idx >> 3) & 63, kx = (int)(idx >> 9) & 1;
    int i = (int)(idx >> 10) & 1, ks = (int)(idx >> 11) & 1, w = (int)(idx >> 12);
    int nl = i * 32 + (l & 31);
    int grow = (nl >> 4) * 1024 + w * 16 + (nl & 15);
    int k = (ks * 2 + kx) * 16 + ((l >> 5) << 3) + j;
    wihEp[idx] = (f16)wihE[grow * 64 + k];
    wihDp[idx] = (f16)wihD[grow * 64 + k];
  }
  // Wfc pack
  for (long long idx = gid; idx < 65536ll; idx += gsz) {
    int j = (int)idx & 7, l = (int)(idx >> 3) & 63, kk = (int)(idx >> 9) & 31;
    int i = (int)(idx >> 14) & 1, ks = (int)(idx >> 15) & 1;
    int o = i * 32 + (l & 31);
    int k = ks * 512 + kk * 16 + ((l >> 5) << 3) + j;
    wfcp[idx] = (f16)wfc[o * 1024 + k];
  }
  // x pack: [t][kkx(4)][b(64)][16]
  for (long long idx = gid; idx < 2097152ll; idx += gsz) {
    int kw = (int)idx & 15, b = (int)(idx >> 4) & 63, kkx = (int)(idx >> 10) & 3, t = (int)(idx >> 12);
    xp[idx] = (f16)x[(long long)b * 32768 + t * 64 + kkx * 16 + kw];
  }
  // y0 pack: [kkx][b][16]
  for (long long idx = gid; idx < 4096ll; idx += gsz) {
    int kw = (int)idx & 15, b = (int)(idx >> 4) & 63, kkx = (int)(idx >> 10) & 3;
    y0p[idx] = (f16)y0[b * 64 + kkx * 16 + kw];
  }
  // combined biases
  for (long long idx = gid; idx < 4096ll; idx += gsz) {
    be[idx] = bihE[idx] + bhhE[idx];
    bd[idx] = bihD[idx] + bhhD[idx];
  }
  // zero the step-release counters (poison is 0xAA..; producers atomicAdd)
  for (long long idx = gid; idx < 561ll * 2; idx += gsz)
    cnt[idx] = 0u;
}

// ============================ persistent LSTM kernel ============================
__device__ __forceinline__ float sigf(float x) { return 1.0f / (1.0f + __expf(-x)); }
__device__ __forceinline__ float tanhfast(float x) {
  x = fminf(fmaxf(x, -15.f), 15.f);
  float e = __expf(2.0f * x);
  return (e - 1.0f) / (e + 1.0f);
}

#define MFMA(a,b,c) __builtin_amdgcn_mfma_f32_32x32x16_f16((a),(b),(c),0,0,0)

__launch_bounds__(256, 1)
__global__ void lstm_persist(char* __restrict__ ws, float* __restrict__ out,
                             const float* __restrict__ bfc)
{
  const int w    = blockIdx.x & 63;   // n-slice: hidden units [w*16, w*16+16)
  const int g    = blockIdx.x >> 6;   // batch group: batches [g*32, g*32+32)
  const int tid  = threadIdx.x;
  const int lane = tid & 63;
  const int q    = tid >> 6;          // wave = K-quarter (k in [q*256, q*256+256))

  const f16* whhEp = (const f16*)(ws + OFF_WHHE) + (size_t)w * 65536;
  const f16* whhDp = (const f16*)(ws + OFF_WHHD) + (size_t)w * 65536;
  const f16* wihEp = (const f16*)(ws + OFF_WIHE) + (size_t)w * 4096;
  const f16* wihDp = (const f16*)(ws + OFF_WIHD) + (size_t)w * 4096;
  const f16* wfcp  = (const f16*)(ws + OFF_WFC);
  const f16* xp    = (const f16*)(ws + OFF_XP);
  const f16* y0p   = (const f16*)(ws + OFF_Y0);
  const float* be  = (const float*)(ws + OFF_BE);
  const float* bd  = (const float*)(ws + OFF_BD);
  unsigned* cnt    = (unsigned*)(ws + OFF_CNT);
  f16* hb          = (f16*)(ws + OFF_H);

  __shared__ float lds_g[4][64][33];   // [K-quarter][n-local][batch-local]
  __shared__ float bias_s[2][64];

  if (tid < 64) {
    int g4 = tid >> 4, u = tid & 15;
    bias_s[0][tid] = be[g4 * 1024 + w * 16 + u];
    bias_s[1][tid] = bd[g4 * 1024 + w * 16 + u];
  }

  // A-frag offsets (row = lane&31, k-halves by lane>>5)
  const int aoff_x = (g * 32 + (lane & 31)) * 16 + (lane >> 5) * 8;  // x pack has b(64)
  const int aoff_h = (lane & 31) * 16 + (lane >> 5) * 8;             // h pack has b(32)
  const int boff   = lane * 8;
  // B-frag base inside a Whh/Wfc pack for this wave's K-quarter
  const int bq = (q >> 1) * 32768 + (q & 1) * 16 * 512;  // + i*16384 + kkq*512 + boff
  // Wih base for this wave
  const int wq = (q >> 1) * 2048 + (q & 1) * 512;        // + i*1024 + boff

  // cell-phase mapping: thread -> (batch bsel, units u0, u0+1)
  const int bsel = tid >> 3;
  const int u0   = (tid & 7) * 2;

  // ---- Whh B-fragments resident in registers ----
  f16x8 bf0[16], bf1[16];
#pragma unroll
  for (int kk = 0; kk < 16; ++kk) {
    bf0[kk] = *(const f16x8*)(whhEp + bq + 0 * 16384 + kk * 512 + boff);
    bf1[kk] = *(const f16x8*)(whhEp + bq + 1 * 16384 + kk * 512 + boff);
  }

  float cA = 0.f, cB = 0.f;   // cell state for (bsel,u0) and (bsel,u0+1)
  __syncthreads();

#pragma unroll 1
  for (int t = 0; t < TOTSTEPS; ++t) {
    const bool enc = (t < T_N);
    if (t == T_N) {
#pragma unroll
      for (int kk = 0; kk < 16; ++kk) {
        bf0[kk] = *(const f16x8*)(whhDp + bq + 0 * 16384 + kk * 512 + boff);
        bf1[kk] = *(const f16x8*)(whhDp + bq + 1 * 16384 + kk * 512 + boff);
      }
    }

    // x-projection operands (independent of h -> issue before the wait)
    const f16* xblk = enc ? (xp + (size_t)t * 4096) : y0p;
    const f16* wihp = enc ? wihEp : wihDp;
    f16x8 xa  = *(const f16x8*)(xblk + q * 1024 + aoff_x);
    f16x8 wfa = *(const f16x8*)(wihp + wq + 0 * 1024 + boff);
    f16x8 wfb = *(const f16x8*)(wihp + wq + 1 * 1024 + boff);

    f32x16 acc0, acc1;
#pragma unroll
    for (int i = 0; i < 16; ++i) { acc0[i] = 0.f; acc1[i] = 0.f; }
    acc0 = MFMA(xa, wfa, acc0);
    acc1 = MFMA(xa, wfb, acc1);

    if (t > 0) {
      // single-lane poll of the aggregated step counter; others park at barrier
      if (tid == 0) {
        while (__hip_atomic_load(cnt + (size_t)t * 2 + g,
                                 __ATOMIC_RELAXED, __HIP_MEMORY_SCOPE_AGENT) < 64u) {}
      }
      __syncthreads();

      const f16* hblk = hb + (size_t)t * 65536 - 65536 + (size_t)g * 32768;
      f16x8 af[16];
#pragma unroll
      for (int kk = 0; kk < 16; ++kk)
        af[kk] = *(const f16x8*)(hblk + (size_t)(q * 16 + kk) * 512 + aoff_h);
#pragma unroll
      for (int kk = 0; kk < 16; ++kk) {
        acc0 = MFMA(af[kk], bf0[kk], acc0);
        acc1 = MFMA(af[kk], bf1[kk], acc1);
      }
    }

    // K-quarter partials to LDS
    {
      const int n0 = lane & 31;
      const int mb = ((lane >> 5) << 2);
#pragma unroll
      for (int r = 0; r < 16; ++r) {
        const int m = mb + (r & 3) + ((r >> 2) << 3);
        lds_g[q][n0][m]      = acc0[r];
        lds_g[q][32 + n0][m] = acc1[r];
      }
    }
    __syncthreads();

    // cell update: (batch bsel, units u0,u0+1); c in fp32 regs
    const float* bs = enc ? bias_s[0] : bias_s[1];
    union { unsigned u32; f16 h2[2]; } hu;
    float cc[2] = {cA, cB};
#pragma unroll
    for (int j = 0; j < 2; ++j) {
      const int u = u0 + j;
      float ig = lds_g[0][u][bsel]      + lds_g[1][u][bsel]      + lds_g[2][u][bsel]      + lds_g[3][u][bsel]      + bs[u];
      float fg = lds_g[0][16 + u][bsel] + lds_g[1][16 + u][bsel] + lds_g[2][16 + u][bsel] + lds_g[3][16 + u][bsel] + bs[16 + u];
      float gg = lds_g[0][32 + u][bsel] + lds_g[1][32 + u][bsel] + lds_g[2][32 + u][bsel] + lds_g[3][32 + u][bsel] + bs[32 + u];
      float og = lds_g[0][48 + u][bsel] + lds_g[1][48 + u][bsel] + lds_g[2][48 + u][bsel] + lds_g[3][48 + u][bsel] + bs[48 + u];
      float cn = sigf(fg) * cc[j] + sigf(ig) * tanhfast(gg);
      cc[j] = cn;
      hu.h2[j] = (f16)(sigf(og) * tanhfast(cn));
    }
    cA = cc[0]; cB = cc[1];

    // contiguous write-through h slice: thread tid -> dword tid of the 1KB block
    {
      f16* dst = hb + (size_t)t * 65536 + (size_t)g * 32768 + (size_t)w * 512 + tid * 2;
      unsigned long long addr = (unsigned long long)(size_t)dst;
      asm volatile("global_store_dword %0, %1, off sc0 sc1" : : "v"(addr), "v"(hu.u32) : "memory");
    }
    asm volatile("s_waitcnt vmcnt(0)" ::: "memory");
    __syncthreads();
    if (tid == 0) {
      (void)__hip_atomic_fetch_add(cnt + (size_t)(t + 1) * 2 + g, 1u,
                                   __ATOMIC_RELEASE, __HIP_MEMORY_SCOPE_AGENT);
    }
  }

  // ---- FC epilogue: WG (g, w<48) -> out[g*32..+32, w*64..+64) from h of step 512+w ----
  if (w < DSTEPS) {
#pragma unroll
    for (int kk = 0; kk < 16; ++kk) {
      bf0[kk] = *(const f16x8*)(wfcp + bq + 0 * 16384 + kk * 512 + boff);
      bf1[kk] = *(const f16x8*)(wfcp + bq + 1 * 16384 + kk * 512 + boff);
    }
    if (tid == 0) {
      while (__hip_atomic_load(cnt + (size_t)(513 + w) * 2 + g,
                               __ATOMIC_RELAXED, __HIP_MEMORY_SCOPE_AGENT) < 64u) {}
    }
    __syncthreads();

    const f16* hblk = hb + (size_t)(512 + w) * 65536 + (size_t)g * 32768;
    f16x8 af[16];
#pragma unroll
    for (int kk = 0; kk < 16; ++kk)
      af[kk] = *(const f16x8*)(hblk + (size_t)(q * 16 + kk) * 512 + aoff_h);

    f32x16 acc0, acc1;
#pragma unroll
    for (int i = 0; i < 16; ++i) { acc0[i] = 0.f; acc1[i] = 0.f; }
#pragma unroll
    for (int kk = 0; kk < 16; ++kk) {
      acc0 = MFMA(af[kk], bf0[kk], acc0);
      acc1 = MFMA(af[kk], bf1[kk], acc1);
    }
    {
      const int n0 = lane & 31;
      const int mb = ((lane >> 5) << 2);
#pragma unroll
      for (int r = 0; r < 16; ++r) {
        const int m = mb + (r & 3) + ((r >> 2) << 3);
        lds_g[q][n0][m]      = acc0[r];
        lds_g[q][32 + n0][m] = acc1[r];
      }
    }
    __syncthreads();
    // thread -> batch bsel, features f0..f0+7
    const int f0 = (tid & 7) * 8;
    float of[8];
#pragma unroll
    for (int j = 0; j < 8; ++j) {
      const int f = f0 + j;
      of[j] = lds_g[0][f][bsel] + lds_g[1][f][bsel] + lds_g[2][f][bsel] + lds_g[3][f][bsel] + bfc[f];
    }
    float* op = out + (size_t)(g * 32 + bsel) * 3072 + w * 64 + f0;
    *(float4*)(op)     = make_float4(of[0], of[1], of[2], of[3]);
    *(float4*)(op + 4) = make_float4(of[4], of[5], of[6], of[7]);
  }
}

// ============================ launch ============================
extern "C" void kernel_launch(void* const* d_in, const int* in_sizes, int n_in,
                              void* d_out, int out_size, void* d_ws, size_t ws_size,
                              hipStream_t stream) {
  const float* x    = (const float*)d_in[0];
  const float* y0   = (const float*)d_in[1];
  const float* wihE = (const float*)d_in[2];
  const float* whhE = (const float*)d_in[3];
  const float* bihE = (const float*)d_in[4];
  const float* bhhE = (const float*)d_in[5];
  const float* wihD = (const float*)d_in[6];
  const float* whhD = (const float*)d_in[7];
  const float* bihD = (const float*)d_in[8];
  const float* bhhD = (const float*)d_in[9];
  const float* wfc  = (const float*)d_in[10];
  const float* bfc  = (const float*)d_in[11];
  char* ws   = (char*)d_ws;
  float* out = (float*)d_out;

  prologue<<<256, 256, 0, stream>>>(x, y0, wihE, whhE, bihE, bhhE,
                                    wihD, whhD, bihD, bhhD, wfc, ws);
  lstm_persist<<<NWG, 256, 0, stream>>>(ws, out, bfc);
}